// Round 9
// baseline (15940.059 us; speedup 1.0000x reference)
//
#include <hip/hip_runtime.h>
#include <hip/hip_bf16.h>

// LSTM persistent kernel, MI355X. B=64, T=2048, D=64, H=512, O=128. K=D+H=576.
// r9 topology: 32 WGs x 256 threads (4 waves, 1 wave/SIMD -> each WG owns a CU,
// up to 512 VGPR/wave, no occupancy constraint). bg = blk&3 (16 batch rows),
// q = blk>>2 (eighth of hidden: 64 dims). Wave wid covers hd0 = q*64+wid*16.
// Gang per bg = 8 WGs (was 32): reader polls 14 remote chunks from 7 WGs and
// takes its own 2 chunks (64 dims) from LDS, synced by __syncthreads.
// Protocol = r4-proven: per-16B-chunk 2-bit generation stamp ((t>>1)&1)+1 in
// LSBs of bf16 elems 6,7; sc1 (device-scope) stores/loads; full-drain
// __syncthreads per step (subsumes store-ack); full reissue of pending chunks.
// Overwrite safety: P stores slot s at t+2 only after P saw gen(t+1) stamps
// from all partner waves, which they store only after reading P's t data.
// hbuf zeroed each launch (stamp 0 never valid) -> no cross-replay ABA.

typedef short short8 __attribute__((ext_vector_type(8)));
typedef float floatx4 __attribute__((ext_vector_type(4)));

#define T_STEPS 2048
#define NBG 4
#define SB() __builtin_amdgcn_sched_barrier(0)

__device__ __forceinline__ unsigned short f2bf(float f){
    unsigned u = __builtin_bit_cast(unsigned, f);
    u += 0x7FFFu + ((u >> 16) & 1u);   // RNE; inputs finite
    return (unsigned short)(u >> 16);
}

__device__ __forceinline__ short8 pack8(float4 a, float4 b){
    short8 s;
    s[0]=(short)f2bf(a.x); s[1]=(short)f2bf(a.y); s[2]=(short)f2bf(a.z); s[3]=(short)f2bf(a.w);
    s[4]=(short)f2bf(b.x); s[5]=(short)f2bf(b.y); s[6]=(short)f2bf(b.z); s[7]=(short)f2bf(b.w);
    return s;
}

__device__ __forceinline__ float fsigmoid(float x){ return 1.0f/(1.0f+__expf(-x)); }
__device__ __forceinline__ float ftanh(float x){ return 2.0f*fsigmoid(2.0f*x)-1.0f; }

// 4 plain cached 16B loads of x chunks (offsets 0,16,128,144 bytes).
__device__ __forceinline__ void xload4(float4* X, const float* base){
    asm volatile(
    "global_load_dwordx4 %0, %4, off\n\t"
    "global_load_dwordx4 %1, %4, off offset:16\n\t"
    "global_load_dwordx4 %2, %4, off offset:128\n\t"
    "global_load_dwordx4 %3, %4, off offset:144"
    : "=&v"(X[0]), "=&v"(X[1]), "=&v"(X[2]), "=&v"(X[3])
    : "v"(base) : "memory");
}

// single device-scope 16B load
__device__ __forceinline__ void hload1_sc1(short8* A, const unsigned short* addr){
    asm volatile("global_load_dwordx4 %0, %1, off sc1"
                 : "=&v"(*A) : "v"(addr) : "memory");
}

// 16 device-scope 16B loads (stride 64B) — final epilogue only.
__device__ __forceinline__ void hload16_sc1(short8* A, const unsigned short* base){
    asm volatile(
    "global_load_dwordx4 %0, %16, off sc1\n\t"
    "global_load_dwordx4 %1, %16, off offset:64 sc1\n\t"
    "global_load_dwordx4 %2, %16, off offset:128 sc1\n\t"
    "global_load_dwordx4 %3, %16, off offset:192 sc1\n\t"
    "global_load_dwordx4 %4, %16, off offset:256 sc1\n\t"
    "global_load_dwordx4 %5, %16, off offset:320 sc1\n\t"
    "global_load_dwordx4 %6, %16, off offset:384 sc1\n\t"
    "global_load_dwordx4 %7, %16, off offset:448 sc1\n\t"
    "global_load_dwordx4 %8, %16, off offset:512 sc1\n\t"
    "global_load_dwordx4 %9, %16, off offset:576 sc1\n\t"
    "global_load_dwordx4 %10, %16, off offset:640 sc1\n\t"
    "global_load_dwordx4 %11, %16, off offset:704 sc1\n\t"
    "global_load_dwordx4 %12, %16, off offset:768 sc1\n\t"
    "global_load_dwordx4 %13, %16, off offset:832 sc1\n\t"
    "global_load_dwordx4 %14, %16, off offset:896 sc1\n\t"
    "global_load_dwordx4 %15, %16, off offset:960 sc1"
    : "=&v"(A[0]), "=&v"(A[1]), "=&v"(A[2]), "=&v"(A[3]),
      "=&v"(A[4]), "=&v"(A[5]), "=&v"(A[6]), "=&v"(A[7]),
      "=&v"(A[8]), "=&v"(A[9]), "=&v"(A[10]), "=&v"(A[11]),
      "=&v"(A[12]), "=&v"(A[13]), "=&v"(A[14]), "=&v"(A[15])
    : "v"(base) : "memory");
}

__global__ __launch_bounds__(256, 1)
void lstm_persist(const float* __restrict__ x,
                  const float* __restrict__ W_ih,
                  const float* __restrict__ W_hh,
                  const float* __restrict__ b_ih,
                  const float* __restrict__ b_hh,
                  const float* __restrict__ W_out,
                  const float* __restrict__ b_out,
                  float* __restrict__ out,
                  unsigned short* __restrict__ hbuf)   // [2][NBG][16][512] bf16
{
    const int blk  = blockIdx.x;
    const int bg   = blk & 3;        // batch group (16 rows)
    const int q    = blk >> 2;       // eighth of hidden dim (64 dims)
    const int tid  = threadIdx.x;
    const int wid  = tid >> 6;       // wave 0..3
    const int lane = tid & 63;
    const int ln   = lane & 15;
    const int lk   = lane >> 4;      // k-chunk 0..3
    const int hd0  = (q << 6) + (wid << 4);   // this wave's 16 hidden dims

    // own quarter tile, double-buffered. [slot][batch 16][local dim 64 +pad]
    // stride 72 shorts = 144 B (16B-aligned rows, odd dword count -> low conflict)
    __shared__ __align__(16) unsigned short hl[2][16][72];

    // ---- stationary B fragments (weights): 64 gate rows x 576 K per wave ----
    short8 bw[4][18];
#pragma unroll
    for (int g = 0; g < 4; ++g){
        const int row = g * 512 + hd0 + ln;
        const float* pih = W_ih + row * 64 + lk * 8;
#pragma unroll
        for (int kk = 0; kk < 2; ++kk){
            float4 u0 = *reinterpret_cast<const float4*>(pih + kk * 32);
            float4 u1 = *reinterpret_cast<const float4*>(pih + kk * 32 + 4);
            bw[g][kk] = pack8(u0, u1);
        }
        const float* phh = W_hh + row * 512 + lk * 8;
#pragma unroll
        for (int kk = 2; kk < 18; ++kk){
            float4 u0 = *reinterpret_cast<const float4*>(phh + (kk - 2) * 32);
            float4 u1 = *reinterpret_cast<const float4*>(phh + (kk - 2) * 32 + 4);
            bw[g][kk] = pack8(u0, u1);
        }
    }

    float bias[4];
#pragma unroll
    for (int g = 0; g < 4; ++g){
        const int col = g * 512 + hd0 + ln;
        bias[g] = b_ih[col] + b_hh[col];
    }

    float c0 = 0.f, c1 = 0.f, c2 = 0.f, c3 = 0.f;
    const int xrow = bg * 16 + ln;

    short8 a[18];
    float4 xr[4];
    xload4(xr, x + ((size_t)xrow * T_STEPS) * 64 + lk * 8);

    for (int t = 0; t < T_STEPS; ++t){
        if (t == 0){ asm volatile("s_waitcnt vmcnt(0)" ::: "memory"); SB(); }
        a[0] = pack8(xr[0], xr[1]);
        a[1] = pack8(xr[2], xr[3]);

        floatx4 acc0 = {bias[0], bias[0], bias[0], bias[0]};
        floatx4 acc1 = {bias[1], bias[1], bias[1], bias[1]};
        floatx4 acc2 = {bias[2], bias[2], bias[2], bias[2]};
        floatx4 acc3 = {bias[3], bias[3], bias[3], bias[3]};
#pragma unroll
        for (int kk = 0; kk < 2; ++kk){
            acc0 = __builtin_amdgcn_mfma_f32_16x16x32_bf16(a[kk], bw[0][kk], acc0, 0, 0, 0);
            acc1 = __builtin_amdgcn_mfma_f32_16x16x32_bf16(a[kk], bw[1][kk], acc1, 0, 0, 0);
            acc2 = __builtin_amdgcn_mfma_f32_16x16x32_bf16(a[kk], bw[2][kk], acc2, 0, 0, 0);
            acc3 = __builtin_amdgcn_mfma_f32_16x16x32_bf16(a[kk], bw[3][kk], acc3, 0, 0, 0);
        }

        if (t > 0){
            const int slot = (t & 1) ^ 1;
            // ---- own eighth (2 chunks, 64 dims) from LDS: barrier-synced ----
#pragma unroll
            for (int c = 0; c < 16; ++c){
                if ((c >> 1) == q){
                    a[c+2] = *reinterpret_cast<const short8*>(
                                 &hl[slot][ln][(c & 1) * 32 + lk * 8]);
                    acc0 = __builtin_amdgcn_mfma_f32_16x16x32_bf16(a[c+2], bw[0][c+2], acc0, 0, 0, 0);
                    acc1 = __builtin_amdgcn_mfma_f32_16x16x32_bf16(a[c+2], bw[1][c+2], acc1, 0, 0, 0);
                    acc2 = __builtin_amdgcn_mfma_f32_16x16x32_bf16(a[c+2], bw[2][c+2], acc2, 0, 0, 0);
                    acc3 = __builtin_amdgcn_mfma_f32_16x16x32_bf16(a[c+2], bw[3][c+2], acc3, 0, 0, 0);
                }
            }
            // ---- remote 14 chunks: issue polls, then x(t+1) prefetch ----
            const unsigned short* hp =
                hbuf + (size_t)((slot * NBG + bg) * 16 + ln) * 512 + lk * 8;
#pragma unroll
            for (int c = 0; c < 16; ++c)
                if ((c >> 1) != q) hload1_sc1(&a[c+2], hp + (size_t)c * 32);
            {
                const int tn = (t + 1 < T_STEPS) ? (t + 1) : t;
                xload4(xr, x + ((size_t)xrow * T_STEPS + (size_t)tn) * 64 + lk * 8);
            }
            // ---- stamp-vote loop (r4 semantics) ----
            unsigned pend = 0xFFFFu & ~(3u << (q * 2));
            const unsigned expst = (((unsigned)(t - 1) >> 1) & 1u) + 1u;
            for (;;){
                asm volatile("s_waitcnt vmcnt(0)" ::: "memory");
                SB();   // rule #18: no vote/MFMA hoists above the wait
                unsigned ready = 0;
#pragma unroll
                for (int c = 0; c < 16; ++c){
                    if ((c >> 1) != q && (pend & (1u << c))){
                        unsigned s = ((unsigned)(unsigned short)a[c+2][6] & 1u)
                                   | (((unsigned)(unsigned short)a[c+2][7] & 1u) << 1);
                        if (__all((int)(s == expst))){
                            ready |= 1u << c;
                            acc0 = __builtin_amdgcn_mfma_f32_16x16x32_bf16(a[c+2], bw[0][c+2], acc0, 0, 0, 0);
                            acc1 = __builtin_amdgcn_mfma_f32_16x16x32_bf16(a[c+2], bw[1][c+2], acc1, 0, 0, 0);
                            acc2 = __builtin_amdgcn_mfma_f32_16x16x32_bf16(a[c+2], bw[2][c+2], acc2, 0, 0, 0);
                            acc3 = __builtin_amdgcn_mfma_f32_16x16x32_bf16(a[c+2], bw[3][c+2], acc3, 0, 0, 0);
                        }
                    }
                }
                pend &= ~ready;
                if (!pend) break;
#pragma unroll
                for (int c = 0; c < 16; ++c)
                    if ((c >> 1) != q && (pend & (1u << c)))
                        hload1_sc1(&a[c+2], hp + (size_t)c * 32);
            }
            SB();
        } else {
            // t == 0: h = 0; just prefetch x(1)
            xload4(xr, x + ((size_t)xrow * T_STEPS + 1) * 64 + lk * 8);
        }

        // epilogue: C/D mapping col(hidden)=lane&15, row(batch)=(lane>>4)*4+reg
#define EPI(R, CREG)                                                         \
        {   float iv = fsigmoid(acc0[R]);                                    \
            float fv_ = fsigmoid(acc1[R]);                                   \
            float gv = ftanh(acc2[R]);                                       \
            float ov = fsigmoid(acc3[R]);                                    \
            CREG = fv_ * CREG + iv * gv;                                     \
            float hv = ov * ftanh(CREG);                                     \
            hl[t & 1][lk * 4 + R][(wid << 4) + ln] = f2bf(hv);               \
            if (t == T_STEPS - 1){                                           \
                int rr = bg * 16 + lk * 4 + R;                               \
                out[8192  + rr * 512 + hd0 + ln] = hv;                       \
                out[40960 + rr * 512 + hd0 + ln] = CREG;                     \
            }                                                                \
        }
        EPI(0, c0) EPI(1, c1) EPI(2, c2) EPI(3, c3)
#undef EPI

        // transposed global store of own 16x16 tile: 32 lanes x 16B, stamped.
        // Reads only THIS wave's hl columns -> compiler's lgkm wait suffices.
        {
            const unsigned stamp = (((unsigned)t >> 1) & 1u) + 1u;
            if (lane < 32){
                const int srow = lane >> 1, shalf = lane & 1;
                short8 v = *reinterpret_cast<const short8*>(
                               &hl[t & 1][srow][(wid << 4) + shalf * 8]);
                v[6] = (short)((v[6] & ~(short)1) | (short)(stamp & 1u));
                v[7] = (short)((v[7] & ~(short)1) | (short)((stamp >> 1) & 1u));
                unsigned short* dst =
                    hbuf + (size_t)(((t & 1) * NBG + bg) * 16 + srow) * 512 + hd0 + shalf * 8;
                asm volatile("global_store_dwordx4 %0, %1, off sc1"
                             :: "v"(dst), "v"(v) : "memory");
            }
        }
        // full drain (store-ack + x prefetch) + intra-WG barrier for hl slot
        __syncthreads();
    }

    // ---- pred = hT @ W_out^T + b_out (q==0, wave 0 of each batch group) ----
    if (q == 0 && wid == 0){
        const unsigned expst = (((unsigned)(T_STEPS - 1) >> 1) & 1u) + 1u;   // = 2
        const unsigned short* hp =
            hbuf + (size_t)((((T_STEPS - 1) & 1) * NBG + bg) * 16 + ln) * 512 + lk * 8;
        short8 ha[16];
        int ok;
        do {
            hload16_sc1(ha, hp);
            asm volatile("s_waitcnt vmcnt(0)" ::: "memory");
            SB();
            ok = 1;
#pragma unroll
            for (int kk = 0; kk < 16; ++kk){
                unsigned s = ((unsigned)(unsigned short)ha[kk][6] & 1u)
                           | (((unsigned)(unsigned short)ha[kk][7] & 1u) << 1);
                ok &= (s == expst) ? 1 : 0;
            }
        } while (!__all(ok));
        SB();
#pragma unroll
        for (int o0 = 0; o0 < 8; ++o0){
            const int col = o0 * 16 + ln;
            const float* wp = W_out + col * 512 + lk * 8;
            floatx4 pa = {0.f, 0.f, 0.f, 0.f};
#pragma unroll
            for (int kk = 0; kk < 16; ++kk){
                float4 w0 = *reinterpret_cast<const float4*>(wp + kk * 32);
                float4 w1 = *reinterpret_cast<const float4*>(wp + kk * 32 + 4);
                pa = __builtin_amdgcn_mfma_f32_16x16x32_bf16(ha[kk], pack8(w0, w1), pa, 0, 0, 0);
            }
            const float bo = b_out[col];
#pragma unroll
            for (int r = 0; r < 4; ++r){
                const int rr = bg * 16 + lk * 4 + r;
                out[rr * 128 + col] = pa[r] + bo;
            }
        }
    }
}

extern "C" void kernel_launch(void* const* d_in, const int* in_sizes, int n_in,
                              void* d_out, int out_size, void* d_ws, size_t ws_size,
                              hipStream_t stream) {
    const float* x     = (const float*)d_in[0];
    const float* W_ih  = (const float*)d_in[1];
    const float* W_hh  = (const float*)d_in[2];
    const float* b_ih  = (const float*)d_in[3];
    const float* b_hh  = (const float*)d_in[4];
    const float* W_out = (const float*)d_in[5];
    const float* b_out = (const float*)d_in[6];

    // ws: [0,128KB) h double-buffer bf16 [2][4][16][512]
    const size_t HBUF_BYTES = (size_t)2 * NBG * 16 * 512 * 2;
    unsigned short* hbuf = (unsigned short*)d_ws;

    // zero stamps each launch: stamp 0 is never valid -> no cross-replay ABA
    hipMemsetAsync(hbuf, 0, HBUF_BYTES, stream);
    lstm_persist<<<dim3(32), dim3(256), 0, stream>>>(
        x, W_ih, W_hh, b_ih, b_hh, W_out, b_out,
        (float*)d_out, hbuf);
}

// Round 10
// 6494.006 us; speedup vs baseline: 2.4546x; 2.4546x over previous
//
#include <hip/hip_runtime.h>
#include <hip/hip_bf16.h>

// LSTM persistent kernel, MI355X. B=64, T=2048, D=64, H=512, O=128. K=D+H=576.
// r10 = r2 protocol (flags + monolithic h load) with three cuts:
//   - DEVICE scope (sc1) everywhere instead of system (sc0 sc1)
//   - flag bump via global_atomic_add sc1 (commits at coherence point)
//   - split-wait h load: vmcnt(8) -> 8 MFMAs -> vmcnt(0) -> 8 MFMAs
// 128 WGs x 64 threads: bg = blockIdx&3 (16 batch rows), gi = blockIdx>>2
// (16 hidden dims = 64 gate rows). Weights stationary in registers.
// Ordering: h stores (sc1) -> vmcnt(0) ack -> atomic flag bump. Readers poll
// flag line (sc1), then monolithic load -> data guaranteed current.
// flags zeroed each launch (monotonic from 0) -> replay-safe, no ABA.

typedef short short8 __attribute__((ext_vector_type(8)));
typedef float floatx4 __attribute__((ext_vector_type(4)));

#define T_STEPS 2048
#define NBG 4
#define NGI 32
#define SB() __builtin_amdgcn_sched_barrier(0)

__device__ __forceinline__ unsigned short f2bf(float f){
    unsigned u = __builtin_bit_cast(unsigned, f);
    u += 0x7FFFu + ((u >> 16) & 1u);   // RNE; inputs finite
    return (unsigned short)(u >> 16);
}

__device__ __forceinline__ short8 pack8(float4 a, float4 b){
    short8 s;
    s[0]=(short)f2bf(a.x); s[1]=(short)f2bf(a.y); s[2]=(short)f2bf(a.z); s[3]=(short)f2bf(a.w);
    s[4]=(short)f2bf(b.x); s[5]=(short)f2bf(b.y); s[6]=(short)f2bf(b.z); s[7]=(short)f2bf(b.w);
    return s;
}

__device__ __forceinline__ float fsigmoid(float x){ return 1.0f/(1.0f+__expf(-x)); }
__device__ __forceinline__ float ftanh(float x){ return 2.0f*fsigmoid(2.0f*x)-1.0f; }

// 4 plain cached 16B loads of x chunks (offsets 0,16,128,144 bytes).
__device__ __forceinline__ void xload4(float4* X, const float* base){
    asm volatile(
    "global_load_dwordx4 %0, %4, off\n\t"
    "global_load_dwordx4 %1, %4, off offset:16\n\t"
    "global_load_dwordx4 %2, %4, off offset:128\n\t"
    "global_load_dwordx4 %3, %4, off offset:144"
    : "=&v"(X[0]), "=&v"(X[1]), "=&v"(X[2]), "=&v"(X[3])
    : "v"(base) : "memory");
}

// 16 device-scope 16B loads (stride 64B), no trailing wait (caller waits).
__device__ __forceinline__ void hload16_sc1(short8* A, const unsigned short* base){
    asm volatile(
    "global_load_dwordx4 %0, %16, off sc1\n\t"
    "global_load_dwordx4 %1, %16, off offset:64 sc1\n\t"
    "global_load_dwordx4 %2, %16, off offset:128 sc1\n\t"
    "global_load_dwordx4 %3, %16, off offset:192 sc1\n\t"
    "global_load_dwordx4 %4, %16, off offset:256 sc1\n\t"
    "global_load_dwordx4 %5, %16, off offset:320 sc1\n\t"
    "global_load_dwordx4 %6, %16, off offset:384 sc1\n\t"
    "global_load_dwordx4 %7, %16, off offset:448 sc1\n\t"
    "global_load_dwordx4 %8, %16, off offset:512 sc1\n\t"
    "global_load_dwordx4 %9, %16, off offset:576 sc1\n\t"
    "global_load_dwordx4 %10, %16, off offset:640 sc1\n\t"
    "global_load_dwordx4 %11, %16, off offset:704 sc1\n\t"
    "global_load_dwordx4 %12, %16, off offset:768 sc1\n\t"
    "global_load_dwordx4 %13, %16, off offset:832 sc1\n\t"
    "global_load_dwordx4 %14, %16, off offset:896 sc1\n\t"
    "global_load_dwordx4 %15, %16, off offset:960 sc1"
    : "=&v"(A[0]), "=&v"(A[1]), "=&v"(A[2]), "=&v"(A[3]),
      "=&v"(A[4]), "=&v"(A[5]), "=&v"(A[6]), "=&v"(A[7]),
      "=&v"(A[8]), "=&v"(A[9]), "=&v"(A[10]), "=&v"(A[11]),
      "=&v"(A[12]), "=&v"(A[13]), "=&v"(A[14]), "=&v"(A[15])
    : "v"(base) : "memory");
}

__global__ __launch_bounds__(64, 1)
void lstm_persist(const float* __restrict__ x,
                  const float* __restrict__ W_ih,
                  const float* __restrict__ W_hh,
                  const float* __restrict__ b_ih,
                  const float* __restrict__ b_hh,
                  const float* __restrict__ W_out,
                  const float* __restrict__ b_out,
                  float* __restrict__ out,
                  unsigned short* __restrict__ hbuf,  // [2][NBG][16][512] bf16
                  unsigned* __restrict__ flags)       // [NBG][NGI] step counters
{
    const int wg   = blockIdx.x;
    const int bg   = wg & 3;         // batch group (16 rows)
    const int gi   = wg >> 2;        // gate group (16 hidden dims)
    const int lane = threadIdx.x;    // 0..63
    const int ln   = lane & 15;
    const int lk   = lane >> 4;      // k-chunk 0..3
    const int hd0  = gi << 4;

    __shared__ __align__(16) unsigned short hl[256];   // 16x16 bf16 transpose tile

    // ---- stationary B fragments (weights) ----
    short8 bw[4][18];
#pragma unroll
    for (int g = 0; g < 4; ++g){
        const int row = g * 512 + hd0 + ln;
        const float* pih = W_ih + row * 64 + lk * 8;
#pragma unroll
        for (int kk = 0; kk < 2; ++kk){
            float4 u0 = *reinterpret_cast<const float4*>(pih + kk * 32);
            float4 u1 = *reinterpret_cast<const float4*>(pih + kk * 32 + 4);
            bw[g][kk] = pack8(u0, u1);
        }
        const float* phh = W_hh + row * 512 + lk * 8;
#pragma unroll
        for (int kk = 2; kk < 18; ++kk){
            float4 u0 = *reinterpret_cast<const float4*>(phh + (kk - 2) * 32);
            float4 u1 = *reinterpret_cast<const float4*>(phh + (kk - 2) * 32 + 4);
            bw[g][kk] = pack8(u0, u1);
        }
    }

    float bias[4];
#pragma unroll
    for (int g = 0; g < 4; ++g){
        const int col = g * 512 + hd0 + ln;
        bias[g] = b_ih[col] + b_hh[col];
    }

    float c0 = 0.f, c1 = 0.f, c2 = 0.f, c3 = 0.f;
    const int xrow = bg * 16 + ln;

    const unsigned* fpoll = flags + bg * NGI + (lane & 31);
    unsigned* fme = flags + bg * NGI + gi;

    short8 a[18];
    float4 xr[4];
    xload4(xr, x + ((size_t)xrow * T_STEPS) * 64 + lk * 8);

    for (int t = 0; t < T_STEPS; ++t){
        if (t > 0){
            // ---- poll flag line (sc1). vmcnt(0) also drains x prefetch,
            //      our h-store ack residue, and the atomic. ----
            unsigned fv;
            do {
                asm volatile("global_load_dword %0, %1, off sc1\n\t"
                             "s_waitcnt vmcnt(0)"
                             : "=v"(fv) : "v"(fpoll) : "memory");
            } while (!__all((int)(fv >= (unsigned)t)));
            SB();
            // ---- monolithic h load (data guaranteed current) ----
            const unsigned short* hp =
                hbuf + (size_t)((((t & 1) ^ 1) * NBG + bg) * 16 + ln) * 512 + lk * 8;
            hload16_sc1(&a[2], hp);
        } else {
            asm volatile("s_waitcnt vmcnt(0)" ::: "memory");
            SB();
        }

        a[0] = pack8(xr[0], xr[1]);
        a[1] = pack8(xr[2], xr[3]);

        floatx4 acc0 = {bias[0], bias[0], bias[0], bias[0]};
        floatx4 acc1 = {bias[1], bias[1], bias[1], bias[1]};
        floatx4 acc2 = {bias[2], bias[2], bias[2], bias[2]};
        floatx4 acc3 = {bias[3], bias[3], bias[3], bias[3]};
        // x-part MFMAs overlap the h-load flight
#pragma unroll
        for (int kk = 0; kk < 2; ++kk){
            acc0 = __builtin_amdgcn_mfma_f32_16x16x32_bf16(a[kk], bw[0][kk], acc0, 0, 0, 0);
            acc1 = __builtin_amdgcn_mfma_f32_16x16x32_bf16(a[kk], bw[1][kk], acc1, 0, 0, 0);
            acc2 = __builtin_amdgcn_mfma_f32_16x16x32_bf16(a[kk], bw[2][kk], acc2, 0, 0, 0);
            acc3 = __builtin_amdgcn_mfma_f32_16x16x32_bf16(a[kk], bw[3][kk], acc3, 0, 0, 0);
        }

        if (t > 0){
            // first 8 h-chunks ready -> MFMA while the rest land
            asm volatile("s_waitcnt vmcnt(8)" ::: "memory");
            SB();
#pragma unroll
            for (int kk = 2; kk < 10; ++kk){
                acc0 = __builtin_amdgcn_mfma_f32_16x16x32_bf16(a[kk], bw[0][kk], acc0, 0, 0, 0);
                acc1 = __builtin_amdgcn_mfma_f32_16x16x32_bf16(a[kk], bw[1][kk], acc1, 0, 0, 0);
                acc2 = __builtin_amdgcn_mfma_f32_16x16x32_bf16(a[kk], bw[2][kk], acc2, 0, 0, 0);
                acc3 = __builtin_amdgcn_mfma_f32_16x16x32_bf16(a[kk], bw[3][kk], acc3, 0, 0, 0);
            }
            asm volatile("s_waitcnt vmcnt(0)" ::: "memory");
            SB();
#pragma unroll
            for (int kk = 10; kk < 18; ++kk){
                acc0 = __builtin_amdgcn_mfma_f32_16x16x32_bf16(a[kk], bw[0][kk], acc0, 0, 0, 0);
                acc1 = __builtin_amdgcn_mfma_f32_16x16x32_bf16(a[kk], bw[1][kk], acc1, 0, 0, 0);
                acc2 = __builtin_amdgcn_mfma_f32_16x16x32_bf16(a[kk], bw[2][kk], acc2, 0, 0, 0);
                acc3 = __builtin_amdgcn_mfma_f32_16x16x32_bf16(a[kk], bw[3][kk], acc3, 0, 0, 0);
            }
        }
        // t == 0: h = 0 contributes nothing; skip h-MFMAs entirely.

        // epilogue: C/D mapping col=lane&15, row=(lane>>4)*4+reg
#define EPI(R, CREG)                                                         \
        {   float iv = fsigmoid(acc0[R]);                                    \
            float fv_ = fsigmoid(acc1[R]);                                   \
            float gv = ftanh(acc2[R]);                                       \
            float ov = fsigmoid(acc3[R]);                                    \
            CREG = fv_ * CREG + iv * gv;                                     \
            float hv = ov * ftanh(CREG);                                     \
            hl[(lk * 4 + R) * 16 + ln] = f2bf(hv);                           \
            if (t == T_STEPS - 1){                                           \
                int rr = bg * 16 + lk * 4 + R;                               \
                out[8192  + rr * 512 + hd0 + ln] = hv;                       \
                out[40960 + rr * 512 + hd0 + ln] = CREG;                     \
            }                                                                \
        }
        EPI(0, c0) EPI(1, c1) EPI(2, c2) EPI(3, c3)
#undef EPI

        // x prefetch for t+1 BEFORE the h store (covered by the ack drain)
        {
            const int tn = (t + 1 < T_STEPS) ? (t + 1) : t;
            xload4(xr, x + ((size_t)xrow * T_STEPS + (size_t)tn) * 64 + lk * 8);
        }

        asm volatile("s_waitcnt lgkmcnt(0)" ::: "memory");   // hl tile complete

        // transposed h store: 32 lanes x 16B, device scope
        if (lane < 32){
            const int row = lane >> 1, half = lane & 1;
            short8 v = *reinterpret_cast<const short8*>(&hl[row * 16 + half * 8]);
            unsigned short* dst =
                hbuf + (size_t)(((t & 1) * NBG + bg) * 16 + row) * 512 + hd0 + half * 8;
            asm volatile("global_store_dwordx4 %0, %1, off sc1"
                         :: "v"(dst), "v"(v) : "memory");
        }
        // ack: h (and x prefetch) complete, then bump flag atomically
        asm volatile("s_waitcnt vmcnt(0)" ::: "memory");
        SB();
        if (lane == 0){
            unsigned one = 1u;
            asm volatile("global_atomic_add %0, %1, off sc1"
                         :: "v"(fme), "v"(one) : "memory");
        }
    }

    // ---- pred = hT @ W_out^T + b_out (gate-group 0 of each batch group) ----
    if (gi == 0){
        unsigned fv;
        do {
            asm volatile("global_load_dword %0, %1, off sc1\n\t"
                         "s_waitcnt vmcnt(0)"
                         : "=v"(fv) : "v"(fpoll) : "memory");
        } while (!__all((int)(fv >= (unsigned)T_STEPS)));
        SB();
        // h_{T-1} is in slot 1
        const unsigned short* hp =
            hbuf + (size_t)((1 * NBG + bg) * 16 + ln) * 512 + lk * 8;
        short8 ha[16];
        hload16_sc1(ha, hp);
        asm volatile("s_waitcnt vmcnt(0)" ::: "memory");
        SB();
#pragma unroll
        for (int o0 = 0; o0 < 8; ++o0){
            const int col = o0 * 16 + ln;
            const float* wp = W_out + col * 512 + lk * 8;
            floatx4 pa = {0.f, 0.f, 0.f, 0.f};
#pragma unroll
            for (int kk = 0; kk < 16; ++kk){
                float4 w0 = *reinterpret_cast<const float4*>(wp + kk * 32);
                float4 w1 = *reinterpret_cast<const float4*>(wp + kk * 32 + 4);
                pa = __builtin_amdgcn_mfma_f32_16x16x32_bf16(ha[kk], pack8(w0, w1), pa, 0, 0, 0);
            }
            const float bo = b_out[col];
#pragma unroll
            for (int r = 0; r < 4; ++r){
                const int rr = bg * 16 + lk * 4 + r;
                out[rr * 128 + col] = pa[r] + bo;
            }
        }
    }
}

extern "C" void kernel_launch(void* const* d_in, const int* in_sizes, int n_in,
                              void* d_out, int out_size, void* d_ws, size_t ws_size,
                              hipStream_t stream) {
    const float* x     = (const float*)d_in[0];
    const float* W_ih  = (const float*)d_in[1];
    const float* W_hh  = (const float*)d_in[2];
    const float* b_ih  = (const float*)d_in[3];
    const float* b_hh  = (const float*)d_in[4];
    const float* W_out = (const float*)d_in[5];
    const float* b_out = (const float*)d_in[6];

    // ws: [0,128KB) h double-buffer bf16 [2][4][16][512]; then flags[128]
    const size_t HBUF_BYTES = (size_t)2 * NBG * 16 * 512 * 2;
    unsigned short* hbuf = (unsigned short*)d_ws;
    unsigned* flags = (unsigned*)((char*)d_ws + HBUF_BYTES);

    hipMemsetAsync(flags, 0, NBG * NGI * sizeof(unsigned), stream);
    lstm_persist<<<dim3(NBG * NGI), dim3(64), 0, stream>>>(
        x, W_ih, W_hh, b_ih, b_hh, W_out, b_out,
        (float*)d_out, hbuf, flags);
}